// Round 12
// baseline (701.954 us; speedup 1.0000x reference)
//
#include <hip/hip_runtime.h>
#include <hip/hip_bf16.h>

#define N_GRAPHS 4096
#define N_ELE 16384
#define EPS 1e-5f

// ws layout (f32 words)
#define A_TAB_OFF 0               // 4096*64 f32 atomic sums
#define A_CNT_OFF 262144          // 4096
#define E_TAB_OFF 266240          // 16384*64
#define E_CNT_OFF 1314816         // 16384
#define STAT_OFF  1331200         // 32 copies * (256 sums + 256 sqs)
#define ZPAD_OFF  1347584         // 16B guaranteed-zero pad (OOB gload_lds target)
#define ZERO_WORDS 1347588        // memset range: everything above
#define A_TABH_OFF 1347600        // 4096*64 bf16 = 131072 words
#define E_TABH_OFF 1478672        // 16384*64 bf16 = 524288 words
#define W1PK_OFF  2002960         // 2 * 128*192 bf16 = 24576 words
#define FCPK_OFF  2027536         // 128*256 bf16 = 16384 words
#define SCALE_OFF 2043920         // 256
#define SHIFT_OFF 2044176         // 256 (contiguous after SCALE)
#define SCR_STAT_OFF 2044432      // ablation scratch stats: 32*512 (values never read)
#define WS_WORDS  2060816         // ~8.24 MB

typedef __attribute__((ext_vector_type(8))) short bf16x8;
typedef __attribute__((ext_vector_type(4))) float f32x4;

__device__ __forceinline__ float bf2f(unsigned s) { return __uint_as_float(s << 16); }
__device__ __forceinline__ unsigned f2bf(float f) {
  unsigned u = __float_as_uint(f);
  return (u + 0x7fffu + ((u >> 16) & 1u)) >> 16;  // RNE
}
__device__ __forceinline__ unsigned pkbf(float a, float b) {
  union { __hip_bfloat16 h; unsigned short u; } ca, cb;
  ca.h = __float2bfloat16(a); cb.h = __float2bfloat16(b);
  return (unsigned)ca.u | ((unsigned)cb.u << 16);
}
__device__ __forceinline__ bf16x8 cvt8(float4 a, float4 b) {
  union { bf16x8 v; unsigned u[4]; } r;
  r.u[0] = pkbf(a.x, a.y); r.u[1] = pkbf(a.z, a.w);
  r.u[2] = pkbf(b.x, b.y); r.u[3] = pkbf(b.z, b.w);
  return r.v;
}
__device__ __forceinline__ void gload16(const void* g, void* l) {
  __builtin_amdgcn_global_load_lds(
      (const __attribute__((address_space(1))) unsigned*)g,
      (__attribute__((address_space(3))) unsigned*)l, 16, 0, 0);
}
__device__ __forceinline__ void sinkf(float v) { asm volatile("" :: "v"(v)); }
__device__ __forceinline__ void sink8(bf16x8 v) {
  uint4 u; __builtin_memcpy(&u, &v, 16);
  asm volatile("" :: "v"(u.x), "v"(u.y), "v"(u.z), "v"(u.w));
}
// bijective XCD-chunk swizzle (m204)
__device__ __forceinline__ int xcd_tile(int bid, int nT) {
  if (nT < 8) return bid;
  int q = nT >> 3, r8 = nT & 7;
  int xcd = bid & 7, i = bid >> 3;
  return (xcd < r8 ? xcd * (q + 1) : r8 * (q + 1) + (xcd - r8) * q) + i;
}

// ---------------- K0: pack W1,W2,fcW to bf16 in MFMA B-fragment order ----------------
__global__ void k_prep(const float* __restrict__ W1, const float* __restrict__ W2,
                       const float* __restrict__ fcW, float* __restrict__ ws) {
  int tid = blockIdx.x * 512 + threadIdx.x;
  if (tid < 49152) {
    unsigned short* wpk = (unsigned short*)(ws + W1PK_OFF);
    int L = tid / 24576, rem = tid % 24576;
    int ct = rem / 3072, rem2 = rem % 3072;
    int i = rem2 >> 9, lane = (rem2 >> 3) & 63, j = rem2 & 7;
    int zkb = L ? (i + 2) : (i < 2 ? i : i + 2);
    int zk = zkb * 32 + ((lane >> 4) << 3) + j;
    int kp = L ? (zk - 64) : (zk < 64 ? zk : zk - 64);
    int col = ct * 16 + (lane & 15);
    const float* W = L ? W2 : W1;
    wpk[tid] = (unsigned short)f2bf(W[col * 192 + kp]);
  } else {
    int idx = tid - 49152;  // 0..32767
    unsigned short* fpk = (unsigned short*)(ws + FCPK_OFF);
    int ct = idx >> 12, kb = (idx >> 9) & 7, lane = (idx >> 3) & 63, j = idx & 7;
    fpk[idx] = (unsigned short)f2bf(fcW[(ct * 16 + (lane & 15)) * 256 + kb * 32 + ((lane >> 4) << 3) + j]);
  }
}

// ---------------- K1: segment sums ----------------
__global__ void k_seg(const float* __restrict__ x, const int* __restrict__ aidx,
                      const int* __restrict__ eidx, float* __restrict__ ws, int N) {
  float* A_tab = ws + A_TAB_OFF; float* A_cnt = ws + A_CNT_OFF;
  float* E_tab = ws + E_TAB_OFF; float* E_cnt = ws + E_CNT_OFF;
  int t = threadIdx.x;
  int c = t & 63, p = (t >> 6) & 1, s = t >> 7;
  int r0 = blockIdx.x * 256;
  int rend = min(r0 + 256, N);
  if (p == 0) {
    float acc = 0.f, cnt = 0.f; int cur = -1;
    for (int r = r0 + s; r < rend; r += 2) {
      int a = aidx[r];
      float v = x[(size_t)r * 128 + c];
      if (a != cur) {
        if (cur >= 0) { atomicAdd(&A_tab[cur * 64 + c], acc); if (c == 0) atomicAdd(&A_cnt[cur], cnt); }
        cur = a; acc = v; cnt = 1.f;
      } else { acc += v; cnt += 1.f; }
    }
    if (cur >= 0) { atomicAdd(&A_tab[cur * 64 + c], acc); if (c == 0) atomicAdd(&A_cnt[cur], cnt); }
  } else {
    for (int r = r0 + s; r < rend; r += 2) {
      int e = eidx[r];
      float v = x[(size_t)r * 128 + 64 + c];
      atomicAdd(&E_tab[e * 64 + c], v);
      if (c == 0) atomicAdd(&E_cnt[e], 1.f);
    }
  }
}

// ---------------- K2: mean + relu -> bf16 tables ----------------
__global__ void k_fin(float* __restrict__ ws) {
  int i = blockIdx.x * 256 + threadIdx.x;
  unsigned* w32 = (unsigned*)ws;
  if (i < 131072) {
    int e = 2 * i;
    float cnt = fmaxf(ws[A_CNT_OFF + (e >> 6)], 1.f);
    float v0 = fmaxf(ws[A_TAB_OFF + e] / cnt, 0.f);
    float v1 = fmaxf(ws[A_TAB_OFF + e + 1] / cnt, 0.f);
    w32[A_TABH_OFF + i] = f2bf(v0) | (f2bf(v1) << 16);
  }
  if (i < 524288) {
    int e = 2 * i;
    float cnt = fmaxf(ws[E_CNT_OFF + (e >> 6)], 1.f);
    float v0 = fmaxf(ws[E_TAB_OFF + e] / cnt, 0.f);
    float v1 = fmaxf(ws[E_TAB_OFF + e + 1] / cnt, 0.f);
    w32[E_TABH_OFF + i] = f2bf(v0) | (f2bf(v1) << 16);
  }
}

// ---------------- K3: MFMA dual GEMM (R11) — templated for phase ablation ----------------
// V=0: full/real. V=1: staging+barrier only. V=2: +B+MFMA. V=3: +stats(scratch).
template<int V>
__global__ __launch_bounds__(512) void k_gemm_t(
    const float* __restrict__ rdf, const float* __restrict__ bdf,
    const int* __restrict__ aidx, const int* __restrict__ eidx,
    float* __restrict__ ws, unsigned* __restrict__ outp, int N, int nT) {
  __shared__ __align__(16) char smem[49152];
  const unsigned short* Atabh = (const unsigned short*)(ws + A_TABH_OFF);
  const unsigned short* Etabh = (const unsigned short*)(ws + E_TABH_OFF);
  const void* zpad = (const void*)(ws + ZPAD_OFF);
  int t = threadIdx.x;
  int l = t & 63, w = t >> 6;
  int tile = xcd_tile(blockIdx.x, nT);
  int row0 = tile * 64;
  int L = w >> 2, ctp = w & 3;
  const unsigned short* WpkL = (const unsigned short*)(ws + W1PK_OFF) + L * 24576;

  // ---- B-frag preload (skipped in V1) ----
  bf16x8 Bfr[12];
  if (V != 1) {
    #pragma unroll
    for (int i = 0; i < 6; ++i)
      #pragma unroll
      for (int cti = 0; cti < 2; ++cti)
        Bfr[i * 2 + cti] = *(const bf16x8*)(WpkL + (((ctp * 2 + cti) * 6 + i) * 64 + l) * 8);
  }

  // ---- all staging via global_load_lds (pre-swizzled per-lane source, linear dest) ----
  #pragma unroll
  for (int ii = 0; ii < 2; ++ii) {
    int rb = (w * 2 + ii) * 4;
    int r = rb + (l >> 4);
    int srow = row0 + r;
    bool ok = srow < N;
    int s = l & 15;
    int c = (s & 8) | ((s ^ r) & 7);
    {
      const void* src;
      if (c < 8) { int ia = ok ? aidx[srow] : 0; src = ok ? (const void*)(Atabh + ((size_t)ia * 64 + c * 8)) : zpad; }
      else       { int ie = ok ? eidx[srow] : 0; src = ok ? (const void*)(Etabh + ((size_t)ie * 64 + (c - 8) * 8)) : zpad; }
      gload16(src, smem + 32768 + rb * 256);
    }
    gload16(ok ? (const void*)(rdf + (size_t)srow * 64 + c * 4) : zpad, smem + rb * 256);
    gload16(ok ? (const void*)(bdf + (size_t)srow * 64 + c * 4) : zpad, smem + 16384 + rb * 256);
  }
  __syncthreads();   // drains vmcnt(0)

  if (V == 1) {      // consume LDS (keep DMA live), sink, exit
    int o = (t * 16) & 16383;
    sink8(*(const bf16x8*)(smem + o));
    sink8(*(const bf16x8*)(smem + 16384 + o));
    sink8(*(const bf16x8*)(smem + 32768 + o));
    return;
  }

  // ---- MFMA ----
  f32x4 acc[4][2];
  #pragma unroll
  for (int mt = 0; mt < 4; ++mt)
    #pragma unroll
    for (int cti = 0; cti < 2; ++cti) acc[mt][cti] = (f32x4){0.f, 0.f, 0.f, 0.f};
  int half = l >> 4;
  #pragma unroll
  for (int i = 0; i < 6; ++i) {
    bf16x8 af[4];
    if (i < 2) {
      const char* region = smem + (L ? 16384 : 0);
      int c0 = i * 8 + half * 2;
      #pragma unroll
      for (int mt = 0; mt < 4; ++mt) {
        int rr = mt * 16 + (l & 15);
        int s0 = (c0 & 8) | ((c0 ^ rr) & 7);
        int s1 = ((c0 + 1) & 8) | (((c0 + 1) ^ rr) & 7);
        float4 fa = *(const float4*)(region + rr * 256 + s0 * 16);
        float4 fb = *(const float4*)(region + rr * 256 + s1 * 16);
        af[mt] = cvt8(fa, fb);
      }
    } else {
      int zkb = i + 2;
      int cl = (zkb * 4 + half) & 15;
      #pragma unroll
      for (int mt = 0; mt < 4; ++mt) {
        int rr = mt * 16 + (l & 15);
        int slot = (cl & 8) | ((cl ^ rr) & 7);
        af[mt] = *(const bf16x8*)(smem + 32768 + rr * 256 + slot * 16);
      }
    }
    #pragma unroll
    for (int cti = 0; cti < 2; ++cti) {
      #pragma unroll
      for (int mt = 0; mt < 4; ++mt)
        acc[mt][cti] = __builtin_amdgcn_mfma_f32_16x16x32_bf16(af[mt], Bfr[i * 2 + cti], acc[mt][cti], 0, 0, 0);
    }
  }

  if (V == 2) {      // sink accumulators, exit (no stats/epilogue)
    #pragma unroll
    for (int mt = 0; mt < 4; ++mt)
      #pragma unroll
      for (int cti = 0; cti < 2; ++cti)
        #pragma unroll
        for (int rr = 0; rr < 4; ++rr) sinkf(acc[mt][cti][rr]);
    return;
  }

  // ---- fused BN stats (V0: real area; V3: scratch) ----
  float* stat = ws + (V == 0 ? STAT_OFF : SCR_STAT_OFF) + (blockIdx.x & 31) * 512;
  #pragma unroll
  for (int cti = 0; cti < 2; ++cti) {
    float s = 0.f, q = 0.f;
    #pragma unroll
    for (int mt = 0; mt < 4; ++mt)
      #pragma unroll
      for (int rr = 0; rr < 4; ++rr) { float v = acc[mt][cti][rr]; s += v; q += v * v; }
    s += __shfl_xor(s, 16); s += __shfl_xor(s, 32);
    q += __shfl_xor(q, 16); q += __shfl_xor(q, 32);
    if (l < 16) {
      int gc = L * 128 + (ctp * 2 + cti) * 16 + l;
      atomicAdd(&stat[gc], s);
      atomicAdd(&stat[256 + gc], q);
    }
  }

  if (V == 3) {
    #pragma unroll
    for (int mt = 0; mt < 4; ++mt)
      #pragma unroll
      for (int cti = 0; cti < 2; ++cti)
        #pragma unroll
        for (int rr = 0; rr < 4; ++rr) sinkf(acc[mt][cti][rr]);
    return;
  }

  __syncthreads();   // all waves done reading z; transpose T reuses smem[0:32K)

  // ---- epilogue: pack bf16 pairs, swizzled LDS transpose ----
  #pragma unroll
  for (int mt = 0; mt < 4; ++mt)
    #pragma unroll
    for (int cti = 0; cti < 2; ++cti)
      #pragma unroll
      for (int rr = 0; rr < 4; ++rr) {
        unsigned ub = pkbf(acc[mt][cti][rr], 0.f) & 0xffffu;
        unsigned pb = (unsigned)__shfl_xor((int)ub, 1);
        if (!(l & 1)) {
          int orow = mt * 16 + ((l >> 4) << 2) + rr;
          int colp = (L * 128 + (ctp * 2 + cti) * 16 + (l & 15)) >> 1;
          int c = colp >> 2;
          int ec = ((c ^ orow) & 7) | (c & 24);
          *(unsigned*)(smem + orow * 512 + ec * 16 + (colp & 3) * 4) = ub | (pb << 16);
        }
      }
  __syncthreads();
  #pragma unroll
  for (int p = 0; p < 4; ++p) {
    int e = p * 512 + t; int rr = e >> 5, v4 = e & 31;
    int ec = ((v4 ^ rr) & 7) | (v4 & 24);
    uint4 val = *(const uint4*)(smem + rr * 512 + ec * 16);
    if (row0 + rr < N) ((uint4*)outp)[(size_t)(row0 + rr) * 32 + v4] = val;
  }
}

// ---------------- K4: BN finalize -> scale/shift ----------------
__global__ void k_bnfin(const float* __restrict__ g1, const float* __restrict__ b1,
                        const float* __restrict__ g2, const float* __restrict__ b2,
                        float* __restrict__ ws, int N) {
  int c = threadIdx.x;  // 256
  float s = 0.f, q = 0.f;
  for (int m = 0; m < 32; ++m) { s += ws[STAT_OFF + m * 512 + c]; q += ws[STAT_OFF + m * 512 + 256 + c]; }
  float inv = 1.f / (float)N;
  float mu = s * inv;
  float var = fmaxf(q * inv - mu * mu, 0.f);
  int lyr = c >> 7, cc = c & 127;
  float ga = lyr ? g2[cc] : g1[cc];
  float be = lyr ? b2[cc] : b1[cc];
  float sc = ga * rsqrtf(var + EPS);
  ws[SCALE_OFF + c] = sc;
  ws[SHIFT_OFF + c] = be - mu * sc;
}

// ---- k_fc staging ----
__device__ __forceinline__ void load_fc(const unsigned* __restrict__ hp, const float* __restrict__ x,
    int row, int g, uint4* hv, float4* xv, int N) {
  if (row < N) {
    const uint4* hs = (const uint4*)((const char*)hp + (size_t)row * 512);
    hv[0] = hs[2 * g]; hv[1] = hs[2 * g + 1]; hv[2] = hs[2 * g + 16]; hv[3] = hs[2 * g + 17];
    const float4* xs = (const float4*)(x + (size_t)row * 128 + g * 16);
    xv[0] = xs[0]; xv[1] = xs[1]; xv[2] = xs[2]; xv[3] = xs[3];
  } else {
    #pragma unroll
    for (int i = 0; i < 4; ++i) { hv[i] = (uint4){0u,0u,0u,0u}; xv[i] = (float4){0.f,0.f,0.f,0.f}; }
  }
}

__device__ __forceinline__ void proc_fc(const uint4* hv, const float4* xv, const float* scsh,
    int r, int g, char* z) {
  const unsigned* hu = (const unsigned*)hv;
  const float* xf = (const float*)xv;
  #pragma unroll
  for (int hh = 0; hh < 2; ++hh) {
    #pragma unroll
    for (int d = 0; d < 2; ++d) {
      uint4 wq;
      unsigned* wu = (unsigned*)&wq;
      #pragma unroll
      for (int jj = 0; jj < 4; ++jj) {
        int xi = d * 8 + 2 * jj;
        int k = g * 16 + hh * 128 + d * 8 + 2 * jj;
        unsigned hraw = hu[hh * 8 + d * 4 + jj];
        float lo = bf2f(hraw & 0xffffu) * scsh[k]     + scsh[256 + k]     + xf[xi];
        float hi = bf2f(hraw >> 16)     * scsh[k + 1] + scsh[256 + k + 1] + xf[xi + 1];
        wu[jj] = pkbf(fmaxf(lo, 0.f), fmaxf(hi, 0.f));
      }
      int c = 2 * g + hh * 16 + d;
      int kb = c >> 2, hf = c & 3;
      int slot = (hf << 3) | ((kb ^ r ^ hf) & 7);
      *(uint4*)(z + r * 512 + slot * 16) = wq;
    }
  }
}

// ---------------- K5: BN+res+relu + MFMA fc GEMM (R10 verbatim) ----------------
__global__ __launch_bounds__(512) void k_fc(
    const float* __restrict__ x, const float* __restrict__ fcb,
    float* __restrict__ ws, float* __restrict__ out, int N, int nT) {
  __shared__ __align__(16) char smem[32768];
  __shared__ float scsh[512];
  int t = threadIdx.x, l = t & 63, w = t >> 6;
  int tile = xcd_tile(blockIdx.x, nT);
  int row0 = tile * 64;
  const unsigned* hp = (const unsigned*)out;
  const unsigned short* Fpk = (const unsigned short*)(ws + FCPK_OFF);
  int half = l >> 4;

  bf16x8 Bfr[8];
  #pragma unroll
  for (int kb = 0; kb < 8; ++kb)
    Bfr[kb] = *(const bf16x8*)(Fpk + ((w * 8 + kb) * 64 + l) * 8);

  scsh[t] = ws[SCALE_OFF + t];
  int rg = t >> 3, g = t & 7;
  uint4 hv[4]; float4 xv[4];
  load_fc(hp, x, row0 + rg, g, hv, xv, N);
  float bias = fcb[(w << 4) + (l & 15)];
  __syncthreads();
  proc_fc(hv, xv, scsh, rg, g, smem);
  __syncthreads();

  f32x4 acc[4];
  #pragma unroll
  for (int mt = 0; mt < 4; ++mt) acc[mt] = (f32x4){0.f, 0.f, 0.f, 0.f};
  #pragma unroll
  for (int kb = 0; kb < 8; ++kb) {
    #pragma unroll
    for (int mt = 0; mt < 4; ++mt) {
      int rr = mt * 16 + (l & 15);
      int slot = ((kb ^ rr ^ half) & 7) | (half << 3);
      bf16x8 af = *(const bf16x8*)(smem + rr * 512 + slot * 16);
      acc[mt] = __builtin_amdgcn_mfma_f32_16x16x32_bf16(af, Bfr[kb], acc[mt], 0, 0, 0);
    }
  }
  __syncthreads();

  #pragma unroll
  for (int mt = 0; mt < 4; ++mt)
    #pragma unroll
    for (int rr = 0; rr < 4; ++rr) {
      int orow = mt * 16 + ((l >> 4) << 2) + rr;
      int col = (w << 4) + (l & 15);
      int ch = col >> 2;
      int cs = ((ch ^ orow) & 7) | (ch & 24);
      *(float*)(smem + orow * 512 + cs * 16 + (col & 3) * 4) = fmaxf(acc[mt][rr] + bias, 0.f);
    }
  __syncthreads();
  #pragma unroll
  for (int p = 0; p < 4; ++p) {
    int e = p * 512 + t; int rr = e >> 5, v4 = e & 31;
    int cs = ((v4 ^ rr) & 7) | (v4 & 24);
    float4 val = *(const float4*)(smem + rr * 512 + cs * 16);
    if (row0 + rr < N) ((float4*)out)[(size_t)(row0 + rr) * 32 + v4] = val;
  }
}

extern "C" void kernel_launch(void* const* d_in, const int* in_sizes, int n_in,
                              void* d_out, int out_size, void* d_ws, size_t ws_size,
                              hipStream_t stream) {
  const float* x    = (const float*)d_in[0];
  const float* rdf  = (const float*)d_in[1];
  const float* bdf  = (const float*)d_in[2];
  const int*   aidx = (const int*)d_in[3];
  const int*   eidx = (const int*)d_in[4];
  const float* rdfW = (const float*)d_in[5];
  const float* rdfG = (const float*)d_in[7];
  const float* rdfBe= (const float*)d_in[8];
  const float* bdfW = (const float*)d_in[9];
  const float* bdfG = (const float*)d_in[11];
  const float* bdfBe= (const float*)d_in[12];
  const float* fcW  = (const float*)d_in[13];
  const float* fcB  = (const float*)d_in[14];
  float* out = (float*)d_out;
  float* ws  = (float*)d_ws;
  int N = in_sizes[0] / 128;
  int nT = (N + 63) / 64;

  hipMemsetAsync(d_ws, 0, (size_t)ZERO_WORDS * 4, stream);
  k_prep<<<160, 512, 0, stream>>>(rdfW, bdfW, fcW, ws);
  k_seg<<<(N + 255) / 256, 256, 0, stream>>>(x, aidx, eidx, ws, N);
  k_fin<<<2048, 256, 0, stream>>>(ws);
  k_gemm_t<0><<<nT, 512, 0, stream>>>(rdf, bdf, aidx, eidx, ws, (unsigned*)d_out, N, nT);
  k_bnfin<<<1, 256, 0, stream>>>(rdfG, rdfBe, bdfG, bdfBe, ws, N);
  k_fc<<<nT, 512, 0, stream>>>(x, fcB, ws, out, N, nT);
  // ---- phase-ablation probes (write only ws scratch; d_out untouched) ----
  k_gemm_t<1><<<nT, 512, 0, stream>>>(rdf, bdf, aidx, eidx, ws, (unsigned*)d_out, N, nT);
  k_gemm_t<2><<<nT, 512, 0, stream>>>(rdf, bdf, aidx, eidx, ws, (unsigned*)d_out, N, nT);
  k_gemm_t<3><<<nT, 512, 0, stream>>>(rdf, bdf, aidx, eidx, ws, (unsigned*)d_out, N, nT);
}

// Round 13
// 426.450 us; speedup vs baseline: 1.6460x; 1.6460x over previous
//
#include <hip/hip_runtime.h>
#include <hip/hip_bf16.h>

#define N_GRAPHS 4096
#define N_ELE 16384
#define EPS 1e-5f

// ws layout (f32 words)
#define A_TAB_OFF 0               // 4096*64 f32 atomic sums
#define A_CNT_OFF 262144          // 4096
#define E_TAB_OFF 266240          // E_tabB: 16384*32 u32 (bf16x2 packed atomic sums)
#define E_CNT_OFF 1314816         // 16384
#define STAT_OFF  1331200         // 32 copies * (256 sums + 256 sqs)
#define ZPAD_OFF  1347584         // 16B guaranteed-zero pad (OOB gload_lds target)
#define ZERO_WORDS 1347588        // memset range: everything above
#define A_TABH_OFF 1347600        // 4096*64 bf16 = 131072 words
#define E_TABH_OFF 1478672        // 16384*64 bf16 = 524288 words
#define W1PK_OFF  2002960         // 2 * 128*192 bf16 = 24576 words
#define FCPK_OFF  2027536         // 128*256 bf16 = 16384 words
#define SCALE_OFF 2043920         // 256
#define SHIFT_OFF 2044176         // 256 (contiguous after SCALE)
#define WS_WORDS  2044432         // ~8.2 MB

typedef __attribute__((ext_vector_type(8))) short bf16x8;
typedef __attribute__((ext_vector_type(4))) float f32x4;

__device__ __forceinline__ float bf2f(unsigned s) { return __uint_as_float(s << 16); }
__device__ __forceinline__ unsigned f2bf(float f) {
  unsigned u = __float_as_uint(f);
  return (u + 0x7fffu + ((u >> 16) & 1u)) >> 16;  // RNE
}
__device__ __forceinline__ unsigned pkbf(float a, float b) {
  union { __hip_bfloat16 h; unsigned short u; } ca, cb;
  ca.h = __float2bfloat16(a); cb.h = __float2bfloat16(b);
  return (unsigned)ca.u | ((unsigned)cb.u << 16);
}
__device__ __forceinline__ bf16x8 cvt8(float4 a, float4 b) {
  union { bf16x8 v; unsigned u[4]; } r;
  r.u[0] = pkbf(a.x, a.y); r.u[1] = pkbf(a.z, a.w);
  r.u[2] = pkbf(b.x, b.y); r.u[3] = pkbf(b.z, b.w);
  return r.v;
}
__device__ __forceinline__ void gload16(const void* g, void* l) {
  __builtin_amdgcn_global_load_lds(
      (const __attribute__((address_space(1))) unsigned*)g,
      (__attribute__((address_space(3))) unsigned*)l, 16, 0, 0);
}
// lane^1 exchange as pure-VALU DPP (quad_perm [1,0,3,2] = ctrl 0xB1) — off the DS pipe
__device__ __forceinline__ unsigned dpp_xor1(unsigned v) {
  return (unsigned)__builtin_amdgcn_mov_dpp((int)v, 0xB1, 0xF, 0xF, true);
}
// bijective XCD-chunk swizzle (m204)
__device__ __forceinline__ int xcd_tile(int bid, int nT) {
  if (nT < 8) return bid;
  int q = nT >> 3, r8 = nT & 7;
  int xcd = bid & 7, i = bid >> 3;
  return (xcd < r8 ? xcd * (q + 1) : r8 * (q + 1) + (xcd - r8) * q) + i;
}

// ---------------- K0: pack W1,W2,fcW to bf16 in MFMA B-fragment order ----------------
__global__ void k_prep(const float* __restrict__ W1, const float* __restrict__ W2,
                       const float* __restrict__ fcW, float* __restrict__ ws) {
  int tid = blockIdx.x * 512 + threadIdx.x;
  if (tid < 49152) {
    unsigned short* wpk = (unsigned short*)(ws + W1PK_OFF);
    int L = tid / 24576, rem = tid % 24576;
    int ct = rem / 3072, rem2 = rem % 3072;
    int i = rem2 >> 9, lane = (rem2 >> 3) & 63, j = rem2 & 7;
    int zkb = L ? (i + 2) : (i < 2 ? i : i + 2);
    int zk = zkb * 32 + ((lane >> 4) << 3) + j;
    int kp = L ? (zk - 64) : (zk < 64 ? zk : zk - 64);
    int col = ct * 16 + (lane & 15);
    const float* W = L ? W2 : W1;
    wpk[tid] = (unsigned short)f2bf(W[col * 192 + kp]);
  } else {
    int idx = tid - 49152;  // 0..32767
    unsigned short* fpk = (unsigned short*)(ws + FCPK_OFF);
    int ct = idx >> 12, kb = (idx >> 9) & 7, lane = (idx >> 3) & 63, j = idx & 7;
    fpk[idx] = (unsigned short)f2bf(fcW[(ct * 16 + (lane & 15)) * 256 + kb * 32 + ((lane >> 4) << 3) + j]);
  }
}

// ---------------- K1: segment sums. A-side: run-length f32 atomics (sorted).
//                  E-side: packed bf16 atomics (2 cols/op, halves atomic line-ops) ----------------
__global__ void k_seg(const float* __restrict__ x, const int* __restrict__ aidx,
                      const int* __restrict__ eidx, float* __restrict__ ws, int N) {
  float* A_tab = ws + A_TAB_OFF; float* A_cnt = ws + A_CNT_OFF;
  unsigned* E_tabB = (unsigned*)(ws + E_TAB_OFF);
  float* E_cnt = ws + E_CNT_OFF;
  int t = threadIdx.x;
  int p = (t >> 6) & 1, s = t >> 7;
  int r0 = blockIdx.x * 256;
  int rend = min(r0 + 256, N);
  if (p == 0) {
    int c = t & 63;
    float acc = 0.f, cnt = 0.f; int cur = -1;
    for (int r = r0 + s; r < rend; r += 2) {
      int a = aidx[r];
      float v = x[(size_t)r * 128 + c];
      if (a != cur) {
        if (cur >= 0) { atomicAdd(&A_tab[cur * 64 + c], acc); if (c == 0) atomicAdd(&A_cnt[cur], cnt); }
        cur = a; acc = v; cnt = 1.f;
      } else { acc += v; cnt += 1.f; }
    }
    if (cur >= 0) { atomicAdd(&A_tab[cur * 64 + c], acc); if (c == 0) atomicAdd(&A_cnt[cur], cnt); }
  } else {
    int sub = (t >> 5) & 1, c2 = t & 31;      // 2 rows per wave-iteration, 32 lanes/row
    for (int r4 = r0 + s * 2; r4 < rend; r4 += 4) {
      int r = r4 + sub;
      if (r < rend) {
        int e = eidx[r];
        float2 v = *(const float2*)(x + (size_t)r * 128 + 64 + 2 * c2);
        unsigned pk = pkbf(v.x, v.y);
        unsigned long long addr = (unsigned long long)(E_tabB + (size_t)e * 32 + c2);
        asm volatile("global_atomic_pk_add_bf16 %0, %1, off" :: "v"(addr), "v"(pk) : "memory");
        if (c2 == 0) atomicAdd(&E_cnt[e], 1.f);
      }
    }
  }
}

// ---------------- K2: mean + relu -> bf16 tables (E source now packed bf16) ----------------
__global__ void k_fin(float* __restrict__ ws) {
  int i = blockIdx.x * 256 + threadIdx.x;
  unsigned* w32 = (unsigned*)ws;
  if (i < 131072) {
    int e = 2 * i;
    float cnt = fmaxf(ws[A_CNT_OFF + (e >> 6)], 1.f);
    float v0 = fmaxf(ws[A_TAB_OFF + e] / cnt, 0.f);
    float v1 = fmaxf(ws[A_TAB_OFF + e + 1] / cnt, 0.f);
    w32[A_TABH_OFF + i] = f2bf(v0) | (f2bf(v1) << 16);
  }
  if (i < 524288) {
    unsigned pk = w32[E_TAB_OFF + i];        // word i: e = i>>5, cols 2*(i&31), +1
    float cnt = fmaxf(ws[E_CNT_OFF + (i >> 5)], 1.f);
    float v0 = fmaxf(bf2f(pk & 0xffffu) / cnt, 0.f);
    float v1 = fmaxf(bf2f(pk >> 16) / cnt, 0.f);
    w32[E_TABH_OFF + i] = f2bf(v0) | (f2bf(v1) << 16);
  }
}

// ---------------- K3: MFMA dual GEMM, all-async staging + B-in-regs + XCD swizzle + DPP epilogue ----------------
__global__ __launch_bounds__(512) void k_gemm(
    const float* __restrict__ rdf, const float* __restrict__ bdf,
    const int* __restrict__ aidx, const int* __restrict__ eidx,
    float* __restrict__ ws, unsigned* __restrict__ outp, int N, int nT) {
  __shared__ __align__(16) char smem[49152];
  const unsigned short* Atabh = (const unsigned short*)(ws + A_TABH_OFF);
  const unsigned short* Etabh = (const unsigned short*)(ws + E_TABH_OFF);
  const void* zpad = (const void*)(ws + ZPAD_OFF);
  int t = threadIdx.x;
  int l = t & 63, w = t >> 6;
  int tile = xcd_tile(blockIdx.x, nT);
  int row0 = tile * 64;
  int L = w >> 2, ctp = w & 3;
  const unsigned short* WpkL = (const unsigned short*)(ws + W1PK_OFF) + L * 24576;

  // ---- B-frag preload: 12 independent L2-hot loads, drained by the staging barrier ----
  bf16x8 Bfr[12];
  #pragma unroll
  for (int i = 0; i < 6; ++i)
    #pragma unroll
    for (int cti = 0; cti < 2; ++cti)
      Bfr[i * 2 + cti] = *(const bf16x8*)(WpkL + (((ctp * 2 + cti) * 6 + i) * 64 + l) * 8);

  // ---- all staging via global_load_lds (pre-swizzled per-lane source, linear dest) ----
  #pragma unroll
  for (int ii = 0; ii < 2; ++ii) {
    int rb = (w * 2 + ii) * 4;
    int r = rb + (l >> 4);
    int srow = row0 + r;
    bool ok = srow < N;
    int s = l & 15;
    int c = (s & 8) | ((s ^ r) & 7);
    {
      const void* src;
      if (c < 8) { int ia = ok ? aidx[srow] : 0; src = ok ? (const void*)(Atabh + ((size_t)ia * 64 + c * 8)) : zpad; }
      else       { int ie = ok ? eidx[srow] : 0; src = ok ? (const void*)(Etabh + ((size_t)ie * 64 + (c - 8) * 8)) : zpad; }
      gload16(src, smem + 32768 + rb * 256);
    }
    gload16(ok ? (const void*)(rdf + (size_t)srow * 64 + c * 4) : zpad, smem + rb * 256);
    gload16(ok ? (const void*)(bdf + (size_t)srow * 64 + c * 4) : zpad, smem + 16384 + rb * 256);
  }
  __syncthreads();   // drains vmcnt(0): all DMA + B-frags

  // ---- MFMA: pure LDS + registers ----
  f32x4 acc[4][2];
  #pragma unroll
  for (int mt = 0; mt < 4; ++mt)
    #pragma unroll
    for (int cti = 0; cti < 2; ++cti) acc[mt][cti] = (f32x4){0.f, 0.f, 0.f, 0.f};
  int half = l >> 4;
  #pragma unroll
  for (int i = 0; i < 6; ++i) {
    bf16x8 af[4];
    if (i < 2) {
      const char* region = smem + (L ? 16384 : 0);
      int c0 = i * 8 + half * 2;
      #pragma unroll
      for (int mt = 0; mt < 4; ++mt) {
        int rr = mt * 16 + (l & 15);
        int s0 = (c0 & 8) | ((c0 ^ rr) & 7);
        int s1 = ((c0 + 1) & 8) | (((c0 + 1) ^ rr) & 7);
        float4 fa = *(const float4*)(region + rr * 256 + s0 * 16);
        float4 fb = *(const float4*)(region + rr * 256 + s1 * 16);
        af[mt] = cvt8(fa, fb);
      }
    } else {
      int zkb = i + 2;
      int cl = (zkb * 4 + half) & 15;
      #pragma unroll
      for (int mt = 0; mt < 4; ++mt) {
        int rr = mt * 16 + (l & 15);
        int slot = (cl & 8) | ((cl ^ rr) & 7);
        af[mt] = *(const bf16x8*)(smem + 32768 + rr * 256 + slot * 16);
      }
    }
    #pragma unroll
    for (int cti = 0; cti < 2; ++cti) {
      #pragma unroll
      for (int mt = 0; mt < 4; ++mt)
        acc[mt][cti] = __builtin_amdgcn_mfma_f32_16x16x32_bf16(af[mt], Bfr[i * 2 + cti], acc[mt][cti], 0, 0, 0);
    }
  }

  // ---- fused BN stats: reduce -> 32-copy atomics ----
  float* stat = ws + STAT_OFF + (blockIdx.x & 31) * 512;
  #pragma unroll
  for (int cti = 0; cti < 2; ++cti) {
    float s = 0.f, q = 0.f;
    #pragma unroll
    for (int mt = 0; mt < 4; ++mt)
      #pragma unroll
      for (int rr = 0; rr < 4; ++rr) { float v = acc[mt][cti][rr]; s += v; q += v * v; }
    s += __shfl_xor(s, 16); s += __shfl_xor(s, 32);
    q += __shfl_xor(q, 16); q += __shfl_xor(q, 32);
    if (l < 16) {
      int gc = L * 128 + (ctp * 2 + cti) * 16 + l;
      atomicAdd(&stat[gc], s);
      atomicAdd(&stat[256 + gc], q);
    }
  }
  __syncthreads();   // all waves done reading z; transpose T [64][512B] reuses smem[0:32K)

  // ---- epilogue: pack bf16 pairs via DPP (VALU, no DS pipe), swizzled LDS transpose ----
  #pragma unroll
  for (int mt = 0; mt < 4; ++mt)
    #pragma unroll
    for (int cti = 0; cti < 2; ++cti)
      #pragma unroll
      for (int rr = 0; rr < 4; ++rr) {
        unsigned ub = pkbf(acc[mt][cti][rr], 0.f) & 0xffffu;
        unsigned pb = dpp_xor1(ub);
        if (!(l & 1)) {
          int orow = mt * 16 + ((l >> 4) << 2) + rr;
          int colp = (L * 128 + (ctp * 2 + cti) * 16 + (l & 15)) >> 1;
          int c = colp >> 2;
          int ec = ((c ^ orow) & 7) | (c & 24);
          *(unsigned*)(smem + orow * 512 + ec * 16 + (colp & 3) * 4) = ub | (pb << 16);
        }
      }
  __syncthreads();
  #pragma unroll
  for (int p = 0; p < 4; ++p) {
    int e = p * 512 + t; int rr = e >> 5, v4 = e & 31;
    int ec = ((v4 ^ rr) & 7) | (v4 & 24);
    uint4 val = *(const uint4*)(smem + rr * 512 + ec * 16);
    if (row0 + rr < N) ((uint4*)outp)[(size_t)(row0 + rr) * 32 + v4] = val;
  }
}

// ---------------- K4: BN finalize -> scale/shift ----------------
__global__ void k_bnfin(const float* __restrict__ g1, const float* __restrict__ b1,
                        const float* __restrict__ g2, const float* __restrict__ b2,
                        float* __restrict__ ws, int N) {
  int c = threadIdx.x;  // 256
  float s = 0.f, q = 0.f;
  for (int m = 0; m < 32; ++m) { s += ws[STAT_OFF + m * 512 + c]; q += ws[STAT_OFF + m * 512 + 256 + c]; }
  float inv = 1.f / (float)N;
  float mu = s * inv;
  float var = fmaxf(q * inv - mu * mu, 0.f);
  int lyr = c >> 7, cc = c & 127;
  float ga = lyr ? g2[cc] : g1[cc];
  float be = lyr ? b2[cc] : b1[cc];
  float sc = ga * rsqrtf(var + EPS);
  ws[SCALE_OFF + c] = sc;
  ws[SHIFT_OFF + c] = be - mu * sc;
}

// ---- k_fc staging (single x read per row, reused for both halves) ----
__device__ __forceinline__ void load_fc(const unsigned* __restrict__ hp, const float* __restrict__ x,
    int row, int g, uint4* hv, float4* xv, int N) {
  if (row < N) {
    const uint4* hs = (const uint4*)((const char*)hp + (size_t)row * 512);
    hv[0] = hs[2 * g]; hv[1] = hs[2 * g + 1]; hv[2] = hs[2 * g + 16]; hv[3] = hs[2 * g + 17];
    const float4* xs = (const float4*)(x + (size_t)row * 128 + g * 16);
    xv[0] = xs[0]; xv[1] = xs[1]; xv[2] = xs[2]; xv[3] = xs[3];
  } else {
    #pragma unroll
    for (int i = 0; i < 4; ++i) { hv[i] = (uint4){0u,0u,0u,0u}; xv[i] = (float4){0.f,0.f,0.f,0.f}; }
  }
}

__device__ __forceinline__ void proc_fc(const uint4* hv, const float4* xv, const float* scsh,
    int r, int g, char* z) {
  const unsigned* hu = (const unsigned*)hv;
  const float* xf = (const float*)xv;
  #pragma unroll
  for (int hh = 0; hh < 2; ++hh) {
    #pragma unroll
    for (int d = 0; d < 2; ++d) {
      uint4 wq;
      unsigned* wu = (unsigned*)&wq;
      #pragma unroll
      for (int jj = 0; jj < 4; ++jj) {
        int xi = d * 8 + 2 * jj;
        int k = g * 16 + hh * 128 + d * 8 + 2 * jj;
        unsigned hraw = hu[hh * 8 + d * 4 + jj];
        float lo = bf2f(hraw & 0xffffu) * scsh[k]     + scsh[256 + k]     + xf[xi];
        float hi = bf2f(hraw >> 16)     * scsh[k + 1] + scsh[256 + k + 1] + xf[xi + 1];
        wu[jj] = pkbf(fmaxf(lo, 0.f), fmaxf(hi, 0.f));
      }
      int c = 2 * g + hh * 16 + d;
      int kb = c >> 2, hf = c & 3;
      int slot = (hf << 3) | ((kb ^ r ^ hf) & 7);
      *(uint4*)(z + r * 512 + slot * 16) = wq;
    }
  }
}

// ---------------- K5: BN+res+relu + MFMA fc GEMM + B-in-regs + swizzle ----------------
__global__ __launch_bounds__(512) void k_fc(
    const float* __restrict__ x, const float* __restrict__ fcb,
    float* __restrict__ ws, float* __restrict__ out, int N, int nT) {
  __shared__ __align__(16) char smem[32768];
  __shared__ float scsh[512];
  int t = threadIdx.x, l = t & 63, w = t >> 6;
  int tile = xcd_tile(blockIdx.x, nT);
  int row0 = tile * 64;
  const unsigned* hp = (const unsigned*)out;
  const unsigned short* Fpk = (const unsigned short*)(ws + FCPK_OFF);
  int half = l >> 4;

  bf16x8 Bfr[8];
  #pragma unroll
  for (int kb = 0; kb < 8; ++kb)
    Bfr[kb] = *(const bf16x8*)(Fpk + ((w * 8 + kb) * 64 + l) * 8);

  scsh[t] = ws[SCALE_OFF + t];
  int rg = t >> 3, g = t & 7;
  uint4 hv[4]; float4 xv[4];
  load_fc(hp, x, row0 + rg, g, hv, xv, N);
  float bias = fcb[(w << 4) + (l & 15)];
  __syncthreads();
  proc_fc(hv, xv, scsh, rg, g, smem);
  __syncthreads();

  f32x4 acc[4];
  #pragma unroll
  for (int mt = 0; mt < 4; ++mt) acc[mt] = (f32x4){0.f, 0.f, 0.f, 0.f};
  #pragma unroll
  for (int kb = 0; kb < 8; ++kb) {
    #pragma unroll
    for (int mt = 0; mt < 4; ++mt) {
      int rr = mt * 16 + (l & 15);
      int slot = ((kb ^ rr ^ half) & 7) | (half << 3);
      bf16x8 af = *(const bf16x8*)(smem + rr * 512 + slot * 16);
      acc[mt] = __builtin_amdgcn_mfma_f32_16x16x32_bf16(af, Bfr[kb], acc[mt], 0, 0, 0);
    }
  }
  __syncthreads();

  #pragma unroll
  for (int mt = 0; mt < 4; ++mt)
    #pragma unroll
    for (int rr = 0; rr < 4; ++rr) {
      int orow = mt * 16 + ((l >> 4) << 2) + rr;
      int col = (w << 4) + (l & 15);
      int ch = col >> 2;
      int cs = ((ch ^ orow) & 7) | (ch & 24);
      *(float*)(smem + orow * 512 + cs * 16 + (col & 3) * 4) = fmaxf(acc[mt][rr] + bias, 0.f);
    }
  __syncthreads();
  #pragma unroll
  for (int p = 0; p < 4; ++p) {
    int e = p * 512 + t; int rr = e >> 5, v4 = e & 31;
    int cs = ((v4 ^ rr) & 7) | (v4 & 24);
    float4 val = *(const float4*)(smem + rr * 512 + cs * 16);
    if (row0 + rr < N) ((float4*)out)[(size_t)(row0 + rr) * 32 + v4] = val;
  }
}

extern "C" void kernel_launch(void* const* d_in, const int* in_sizes, int n_in,
                              void* d_out, int out_size, void* d_ws, size_t ws_size,
                              hipStream_t stream) {
  const float* x    = (const float*)d_in[0];
  const float* rdf  = (const float*)d_in[1];
  const float* bdf  = (const float*)d_in[2];
  const int*   aidx = (const int*)d_in[3];
  const int*   eidx = (const int*)d_in[4];
  const float* rdfW = (const float*)d_in[5];
  const float* rdfG = (const float*)d_in[7];
  const float* rdfBe= (const float*)d_in[8];
  const float* bdfW = (const float*)d_in[9];
  const float* bdfG = (const float*)d_in[11];
  const float* bdfBe= (const float*)d_in[12];
  const float* fcW  = (const float*)d_in[13];
  const float* fcB  = (const float*)d_in[14];
  float* out = (float*)d_out;
  float* ws  = (float*)d_ws;
  int N = in_sizes[0] / 128;
  int nT = (N + 63) / 64;

  hipMemsetAsync(d_ws, 0, (size_t)ZERO_WORDS * 4, stream);
  k_prep<<<160, 512, 0, stream>>>(rdfW, bdfW, fcW, ws);
  k_seg<<<(N + 255) / 256, 256, 0, stream>>>(x, aidx, eidx, ws, N);
  k_fin<<<2048, 256, 0, stream>>>(ws);
  k_gemm<<<nT, 512, 0, stream>>>(rdf, bdf, aidx, eidx, ws, (unsigned*)d_out, N, nT);
  k_bnfin<<<1, 256, 0, stream>>>(rdfG, rdfBe, bdfG, bdfBe, ws, N);
  k_fc<<<nT, 512, 0, stream>>>(x, fcB, ws, out, N, nT);
}

// Round 15
// 415.881 us; speedup vs baseline: 1.6879x; 1.0254x over previous
//
#include <hip/hip_runtime.h>
#include <hip/hip_bf16.h>

#define N_GRAPHS 4096
#define N_ELE 16384
#define EPS 1e-5f

// ws layout (f32 words)
#define A_TAB_OFF 0               // 4096*64 f32 atomic sums
#define A_CNT_OFF 262144          // 4096
#define E_TAB_OFF 266240          // E_tabB: 16384*32 u32 (bf16x2 packed atomic sums)
#define E_CNT_OFF 1314816         // 16384
#define STAT_OFF  1331200         // 32 copies * (256 sums + 256 sqs)
#define ZPAD_OFF  1347584         // 16B guaranteed-zero pad (OOB gload_lds target)
#define ZERO_WORDS 1347588        // memset range: everything above
#define A_TABH_OFF 1347600        // 4096*64 bf16 = 131072 words
#define E_TABH_OFF 1478672        // 16384*64 bf16 = 524288 words
#define W1PK_OFF  2002960         // 2 * 128*192 bf16 = 24576 words
#define FCPK_OFF  2027536         // 128*256 bf16 = 16384 words
#define SCALE_OFF 2043920         // 256
#define SHIFT_OFF 2044176         // 256 (contiguous after SCALE)
#define WS_WORDS  2044432         // ~8.2 MB

typedef __attribute__((ext_vector_type(8))) short bf16x8;
typedef __attribute__((ext_vector_type(4))) float f32x4;

__device__ __forceinline__ float bf2f(unsigned s) { return __uint_as_float(s << 16); }
__device__ __forceinline__ unsigned f2bf(float f) {
  unsigned u = __float_as_uint(f);
  return (u + 0x7fffu + ((u >> 16) & 1u)) >> 16;  // RNE
}
__device__ __forceinline__ unsigned pkbf(float a, float b) {
  union { __hip_bfloat16 h; unsigned short u; } ca, cb;
  ca.h = __float2bfloat16(a); cb.h = __float2bfloat16(b);
  return (unsigned)ca.u | ((unsigned)cb.u << 16);
}
__device__ __forceinline__ bf16x8 cvt8(float4 a, float4 b) {
  union { bf16x8 v; unsigned u[4]; } r;
  r.u[0] = pkbf(a.x, a.y); r.u[1] = pkbf(a.z, a.w);
  r.u[2] = pkbf(b.x, b.y); r.u[3] = pkbf(b.z, b.w);
  return r.v;
}
__device__ __forceinline__ void gload16(const void* g, void* l) {
  __builtin_amdgcn_global_load_lds(
      (const __attribute__((address_space(1))) unsigned*)g,
      (__attribute__((address_space(3))) unsigned*)l, 16, 0, 0);
}
__device__ __forceinline__ void atomic_pk_bf16(unsigned* p, unsigned pk) {
  asm volatile("global_atomic_pk_add_bf16 %0, %1, off"
               :: "v"((unsigned long long)p), "v"(pk) : "memory");
}
// lane^1 exchange as pure-VALU DPP (quad_perm [1,0,3,2] = ctrl 0xB1) — off the DS pipe
__device__ __forceinline__ unsigned dpp_xor1(unsigned v) {
  return (unsigned)__builtin_amdgcn_mov_dpp((int)v, 0xB1, 0xF, 0xF, true);
}
// bijective XCD-chunk swizzle (m204)
__device__ __forceinline__ int xcd_tile(int bid, int nT) {
  if (nT < 8) return bid;
  int q = nT >> 3, r8 = nT & 7;
  int xcd = bid & 7, i = bid >> 3;
  return (xcd < r8 ? xcd * (q + 1) : r8 * (q + 1) + (xcd - r8) * q) + i;
}

// ---------------- K0: pack W1,W2,fcW to bf16 in MFMA B-fragment order ----------------
__global__ void k_prep(const float* __restrict__ W1, const float* __restrict__ W2,
                       const float* __restrict__ fcW, float* __restrict__ ws) {
  int tid = blockIdx.x * 512 + threadIdx.x;
  if (tid < 49152) {
    unsigned short* wpk = (unsigned short*)(ws + W1PK_OFF);
    int L = tid / 24576, rem = tid % 24576;
    int ct = rem / 3072, rem2 = rem % 3072;
    int i = rem2 >> 9, lane = (rem2 >> 3) & 63, j = rem2 & 7;
    int zkb = L ? (i + 2) : (i < 2 ? i : i + 2);
    int zk = zkb * 32 + ((lane >> 4) << 3) + j;
    int kp = L ? (zk - 64) : (zk < 64 ? zk : zk - 64);
    int col = ct * 16 + (lane & 15);
    const float* W = L ? W2 : W1;
    wpk[tid] = (unsigned short)f2bf(W[col * 192 + kp]);
  } else {
    int idx = tid - 49152;  // 0..32767
    unsigned short* fpk = (unsigned short*)(ws + FCPK_OFF);
    int ct = idx >> 12, kb = (idx >> 9) & 7, lane = (idx >> 3) & 63, j = idx & 7;
    fpk[idx] = (unsigned short)f2bf(fcW[(ct * 16 + (lane & 15)) * 256 + kb * 32 + ((lane >> 4) << 3) + j]);
  }
}

// ---------------- K1: segment sums — unified 512B row loads (R14 win kept).
// lanes 0-31: A-side run-length, f32 atomic flushes (R13-proven path).
// lanes 32-63: E-side pk-bf16 atomics (R13-proven). Explicit vmcnt drain at exit. ----------------
__global__ void k_seg(const float* __restrict__ x, const int* __restrict__ aidx,
                      const int* __restrict__ eidx, float* __restrict__ ws, int N) {
  float* A_tab = ws + A_TAB_OFF; float* A_cnt = ws + A_CNT_OFF;
  unsigned* E_tabB = (unsigned*)(ws + E_TAB_OFF);
  float* E_cnt = ws + E_CNT_OFF;
  int t = threadIdx.x, w = t >> 6, l = t & 63;
  int r0 = blockIdx.x * 256;
  int rend = min(r0 + 256, N);
  float ax = 0.f, ay = 0.f, cnt = 0.f;
  int cur = -1;
  int le = l & 31;
  for (int r = r0 + w; r < rend; r += 4) {
    float2 v = *(const float2*)(x + (size_t)r * 128 + 2 * l);   // 64 lanes -> one 512B txn
    if (l < 32) {
      int a = aidx[r];
      if (a != cur) {
        if (cur >= 0) {
          atomicAdd(&A_tab[cur * 64 + 2 * l], ax);
          atomicAdd(&A_tab[cur * 64 + 2 * l + 1], ay);
          if (l == 0) atomicAdd(&A_cnt[cur], cnt);
        }
        cur = a; ax = v.x; ay = v.y; cnt = 1.f;
      } else { ax += v.x; ay += v.y; cnt += 1.f; }
    } else {
      int e = eidx[r];
      atomic_pk_bf16(E_tabB + (size_t)e * 32 + le, pkbf(v.x, v.y));
      if (le == 0) atomicAdd(&E_cnt[e], 1.f);
    }
  }
  if (cur >= 0) {
    atomicAdd(&A_tab[cur * 64 + 2 * l], ax);
    atomicAdd(&A_tab[cur * 64 + 2 * l + 1], ay);
    if (l == 0) atomicAdd(&A_cnt[cur], cnt);
  }
  asm volatile("s_waitcnt vmcnt(0)" ::: "memory");   // drain asm-issued atomics before wave exit
}

// ---------------- K2: mean + relu -> bf16 tables (A: f32 source; E: packed bf16 source) ----------------
__global__ void k_fin(float* __restrict__ ws) {
  int i = blockIdx.x * 256 + threadIdx.x;
  unsigned* w32 = (unsigned*)ws;
  if (i < 131072) {
    int e = 2 * i;
    float cnt = fmaxf(ws[A_CNT_OFF + (e >> 6)], 1.f);
    float v0 = fmaxf(ws[A_TAB_OFF + e] / cnt, 0.f);
    float v1 = fmaxf(ws[A_TAB_OFF + e + 1] / cnt, 0.f);
    w32[A_TABH_OFF + i] = f2bf(v0) | (f2bf(v1) << 16);
  }
  if (i < 524288) {
    unsigned pk = w32[E_TAB_OFF + i];        // word i: e = i>>5, cols 2*(i&31), +1
    float cnt = fmaxf(ws[E_CNT_OFF + (i >> 5)], 1.f);
    float v0 = fmaxf(bf2f(pk & 0xffffu) / cnt, 0.f);
    float v1 = fmaxf(bf2f(pk >> 16) / cnt, 0.f);
    w32[E_TABH_OFF + i] = f2bf(v0) | (f2bf(v1) << 16);
  }
}

// ---------------- K3: MFMA dual GEMM (R13 verbatim) ----------------
__global__ __launch_bounds__(512) void k_gemm(
    const float* __restrict__ rdf, const float* __restrict__ bdf,
    const int* __restrict__ aidx, const int* __restrict__ eidx,
    float* __restrict__ ws, unsigned* __restrict__ outp, int N, int nT) {
  __shared__ __align__(16) char smem[49152];
  const unsigned short* Atabh = (const unsigned short*)(ws + A_TABH_OFF);
  const unsigned short* Etabh = (const unsigned short*)(ws + E_TABH_OFF);
  const void* zpad = (const void*)(ws + ZPAD_OFF);
  int t = threadIdx.x;
  int l = t & 63, w = t >> 6;
  int tile = xcd_tile(blockIdx.x, nT);
  int row0 = tile * 64;
  int L = w >> 2, ctp = w & 3;
  const unsigned short* WpkL = (const unsigned short*)(ws + W1PK_OFF) + L * 24576;

  bf16x8 Bfr[12];
  #pragma unroll
  for (int i = 0; i < 6; ++i)
    #pragma unroll
    for (int cti = 0; cti < 2; ++cti)
      Bfr[i * 2 + cti] = *(const bf16x8*)(WpkL + (((ctp * 2 + cti) * 6 + i) * 64 + l) * 8);

  #pragma unroll
  for (int ii = 0; ii < 2; ++ii) {
    int rb = (w * 2 + ii) * 4;
    int r = rb + (l >> 4);
    int srow = row0 + r;
    bool ok = srow < N;
    int s = l & 15;
    int c = (s & 8) | ((s ^ r) & 7);
    {
      const void* src;
      if (c < 8) { int ia = ok ? aidx[srow] : 0; src = ok ? (const void*)(Atabh + ((size_t)ia * 64 + c * 8)) : zpad; }
      else       { int ie = ok ? eidx[srow] : 0; src = ok ? (const void*)(Etabh + ((size_t)ie * 64 + (c - 8) * 8)) : zpad; }
      gload16(src, smem + 32768 + rb * 256);
    }
    gload16(ok ? (const void*)(rdf + (size_t)srow * 64 + c * 4) : zpad, smem + rb * 256);
    gload16(ok ? (const void*)(bdf + (size_t)srow * 64 + c * 4) : zpad, smem + 16384 + rb * 256);
  }
  __syncthreads();

  f32x4 acc[4][2];
  #pragma unroll
  for (int mt = 0; mt < 4; ++mt)
    #pragma unroll
    for (int cti = 0; cti < 2; ++cti) acc[mt][cti] = (f32x4){0.f, 0.f, 0.f, 0.f};
  int half = l >> 4;
  #pragma unroll
  for (int i = 0; i < 6; ++i) {
    bf16x8 af[4];
    if (i < 2) {
      const char* region = smem + (L ? 16384 : 0);
      int c0 = i * 8 + half * 2;
      #pragma unroll
      for (int mt = 0; mt < 4; ++mt) {
        int rr = mt * 16 + (l & 15);
        int s0 = (c0 & 8) | ((c0 ^ rr) & 7);
        int s1 = ((c0 + 1) & 8) | (((c0 + 1) ^ rr) & 7);
        float4 fa = *(const float4*)(region + rr * 256 + s0 * 16);
        float4 fb = *(const float4*)(region + rr * 256 + s1 * 16);
        af[mt] = cvt8(fa, fb);
      }
    } else {
      int zkb = i + 2;
      int cl = (zkb * 4 + half) & 15;
      #pragma unroll
      for (int mt = 0; mt < 4; ++mt) {
        int rr = mt * 16 + (l & 15);
        int slot = (cl & 8) | ((cl ^ rr) & 7);
        af[mt] = *(const bf16x8*)(smem + 32768 + rr * 256 + slot * 16);
      }
    }
    #pragma unroll
    for (int cti = 0; cti < 2; ++cti) {
      #pragma unroll
      for (int mt = 0; mt < 4; ++mt)
        acc[mt][cti] = __builtin_amdgcn_mfma_f32_16x16x32_bf16(af[mt], Bfr[i * 2 + cti], acc[mt][cti], 0, 0, 0);
    }
  }

  float* stat = ws + STAT_OFF + (blockIdx.x & 31) * 512;
  #pragma unroll
  for (int cti = 0; cti < 2; ++cti) {
    float s = 0.f, q = 0.f;
    #pragma unroll
    for (int mt = 0; mt < 4; ++mt)
      #pragma unroll
      for (int rr = 0; rr < 4; ++rr) { float v = acc[mt][cti][rr]; s += v; q += v * v; }
    s += __shfl_xor(s, 16); s += __shfl_xor(s, 32);
    q += __shfl_xor(q, 16); q += __shfl_xor(q, 32);
    if (l < 16) {
      int gc = L * 128 + (ctp * 2 + cti) * 16 + l;
      atomicAdd(&stat[gc], s);
      atomicAdd(&stat[256 + gc], q);
    }
  }
  __syncthreads();

  #pragma unroll
  for (int mt = 0; mt < 4; ++mt)
    #pragma unroll
    for (int cti = 0; cti < 2; ++cti)
      #pragma unroll
      for (int rr = 0; rr < 4; ++rr) {
        unsigned ub = pkbf(acc[mt][cti][rr], 0.f) & 0xffffu;
        unsigned pb = dpp_xor1(ub);
        if (!(l & 1)) {
          int orow = mt * 16 + ((l >> 4) << 2) + rr;
          int colp = (L * 128 + (ctp * 2 + cti) * 16 + (l & 15)) >> 1;
          int c = colp >> 2;
          int ec = ((c ^ orow) & 7) | (c & 24);
          *(unsigned*)(smem + orow * 512 + ec * 16 + (colp & 3) * 4) = ub | (pb << 16);
        }
      }
  __syncthreads();
  #pragma unroll
  for (int p = 0; p < 4; ++p) {
    int e = p * 512 + t; int rr = e >> 5, v4 = e & 31;
    int ec = ((v4 ^ rr) & 7) | (v4 & 24);
    uint4 val = *(const uint4*)(smem + rr * 512 + ec * 16);
    if (row0 + rr < N) ((uint4*)outp)[(size_t)(row0 + rr) * 32 + v4] = val;
  }
}

// ---------------- K4: BN finalize -> scale/shift ----------------
__global__ void k_bnfin(const float* __restrict__ g1, const float* __restrict__ b1,
                        const float* __restrict__ g2, const float* __restrict__ b2,
                        float* __restrict__ ws, int N) {
  int c = threadIdx.x;  // 256
  float s = 0.f, q = 0.f;
  for (int m = 0; m < 32; ++m) { s += ws[STAT_OFF + m * 512 + c]; q += ws[STAT_OFF + m * 512 + 256 + c]; }
  float inv = 1.f / (float)N;
  float mu = s * inv;
  float var = fmaxf(q * inv - mu * mu, 0.f);
  int lyr = c >> 7, cc = c & 127;
  float ga = lyr ? g2[cc] : g1[cc];
  float be = lyr ? b2[cc] : b1[cc];
  float sc = ga * rsqrtf(var + EPS);
  ws[SCALE_OFF + c] = sc;
  ws[SHIFT_OFF + c] = be - mu * sc;
}

// ---- k_fc staging (single x read per row, reused for both halves) ----
__device__ __forceinline__ void load_fc(const unsigned* __restrict__ hp, const float* __restrict__ x,
    int row, int g, uint4* hv, float4* xv, int N) {
  if (row < N) {
    const uint4* hs = (const uint4*)((const char*)hp + (size_t)row * 512);
    hv[0] = hs[2 * g]; hv[1] = hs[2 * g + 1]; hv[2] = hs[2 * g + 16]; hv[3] = hs[2 * g + 17];
    const float4* xs = (const float4*)(x + (size_t)row * 128 + g * 16);
    xv[0] = xs[0]; xv[1] = xs[1]; xv[2] = xs[2]; xv[3] = xs[3];
  } else {
    #pragma unroll
    for (int i = 0; i < 4; ++i) { hv[i] = (uint4){0u,0u,0u,0u}; xv[i] = (float4){0.f,0.f,0.f,0.f}; }
  }
}

__device__ __forceinline__ void proc_fc(const uint4* hv, const float4* xv, const float* scsh,
    int r, int g, char* z) {
  const unsigned* hu = (const unsigned*)hv;
  const float* xf = (const float*)xv;
  #pragma unroll
  for (int hh = 0; hh < 2; ++hh) {
    #pragma unroll
    for (int d = 0; d < 2; ++d) {
      uint4 wq;
      unsigned* wu = (unsigned*)&wq;
      #pragma unroll
      for (int jj = 0; jj < 4; ++jj) {
        int xi = d * 8 + 2 * jj;
        int k = g * 16 + hh * 128 + d * 8 + 2 * jj;
        unsigned hraw = hu[hh * 8 + d * 4 + jj];
        float lo = bf2f(hraw & 0xffffu) * scsh[k]     + scsh[256 + k]     + xf[xi];
        float hi = bf2f(hraw >> 16)     * scsh[k + 1] + scsh[256 + k + 1] + xf[xi + 1];
        wu[jj] = pkbf(fmaxf(lo, 0.f), fmaxf(hi, 0.f));
      }
      int c = 2 * g + hh * 16 + d;
      int kb = c >> 2, hf = c & 3;
      int slot = (hf << 3) | ((kb ^ r ^ hf) & 7);
      *(uint4*)(z + r * 512 + slot * 16) = wq;
    }
  }
}

// ---------------- K5: BN+res+relu + MFMA fc GEMM (R13 verbatim) ----------------
__global__ __launch_bounds__(512) void k_fc(
    const float* __restrict__ x, const float* __restrict__ fcb,
    float* __restrict__ ws, float* __restrict__ out, int N, int nT) {
  __shared__ __align__(16) char smem[32768];
  __shared__ float scsh[512];
  int t = threadIdx.x, l = t & 63, w = t >> 6;
  int tile = xcd_tile(blockIdx.x, nT);
  int row0 = tile * 64;
  const unsigned* hp = (const unsigned*)out;
  const unsigned short* Fpk = (const unsigned short*)(ws + FCPK_OFF);
  int half = l >> 4;

  bf16x8 Bfr[8];
  #pragma unroll
  for (int kb = 0; kb < 8; ++kb)
    Bfr[kb] = *(const bf16x8*)(Fpk + ((w * 8 + kb) * 64 + l) * 8);

  scsh[t] = ws[SCALE_OFF + t];
  int rg = t >> 3, g = t & 7;
  uint4 hv[4]; float4 xv[4];
  load_fc(hp, x, row0 + rg, g, hv, xv, N);
  float bias = fcb[(w << 4) + (l & 15)];
  __syncthreads();
  proc_fc(hv, xv, scsh, rg, g, smem);
  __syncthreads();

  f32x4 acc[4];
  #pragma unroll
  for (int mt = 0; mt < 4; ++mt) acc[mt] = (f32x4){0.f, 0.f, 0.f, 0.f};
  #pragma unroll
  for (int kb = 0; kb < 8; ++kb) {
    #pragma unroll
    for (int mt = 0; mt < 4; ++mt) {
      int rr = mt * 16 + (l & 15);
      int slot = ((kb ^ rr ^ half) & 7) | (half << 3);
      bf16x8 af = *(const bf16x8*)(smem + rr * 512 + slot * 16);
      acc[mt] = __builtin_amdgcn_mfma_f32_16x16x32_bf16(af, Bfr[kb], acc[mt], 0, 0, 0);
    }
  }
  __syncthreads();

  #pragma unroll
  for (int mt = 0; mt < 4; ++mt)
    #pragma unroll
    for (int rr = 0; rr < 4; ++rr) {
      int orow = mt * 16 + ((l >> 4) << 2) + rr;
      int col = (w << 4) + (l & 15);
      int ch = col >> 2;
      int cs = ((ch ^ orow) & 7) | (ch & 24);
      *(float*)(smem + orow * 512 + cs * 16 + (col & 3) * 4) = fmaxf(acc[mt][rr] + bias, 0.f);
    }
  __syncthreads();
  #pragma unroll
  for (int p = 0; p < 4; ++p) {
    int e = p * 512 + t; int rr = e >> 5, v4 = e & 31;
    int cs = ((v4 ^ rr) & 7) | (v4 & 24);
    float4 val = *(const float4*)(smem + rr * 512 + cs * 16);
    if (row0 + rr < N) ((float4*)out)[(size_t)(row0 + rr) * 32 + v4] = val;
  }
}

extern "C" void kernel_launch(void* const* d_in, const int* in_sizes, int n_in,
                              void* d_out, int out_size, void* d_ws, size_t ws_size,
                              hipStream_t stream) {
  const float* x    = (const float*)d_in[0];
  const float* rdf  = (const float*)d_in[1];
  const float* bdf  = (const float*)d_in[2];
  const int*   aidx = (const int*)d_in[3];
  const int*   eidx = (const int*)d_in[4];
  const float* rdfW = (const float*)d_in[5];
  const float* rdfG = (const float*)d_in[7];
  const float* rdfBe= (const float*)d_in[8];
  const float* bdfW = (const float*)d_in[9];
  const float* bdfG = (const float*)d_in[11];
  const float* bdfBe= (const float*)d_in[12];
  const float* fcW  = (const float*)d_in[13];
  const float* fcB  = (const float*)d_in[14];
  float* out = (float*)d_out;
  float* ws  = (float*)d_ws;
  int N = in_sizes[0] / 128;
  int nT = (N + 63) / 64;

  hipMemsetAsync(d_ws, 0, (size_t)ZERO_WORDS * 4, stream);
  k_prep<<<160, 512, 0, stream>>>(rdfW, bdfW, fcW, ws);
  k_seg<<<(N + 255) / 256, 256, 0, stream>>>(x, aidx, eidx, ws, N);
  k_fin<<<2048, 256, 0, stream>>>(ws);
  k_gemm<<<nT, 512, 0, stream>>>(rdf, bdf, aidx, eidx, ws, (unsigned*)d_out, N, nT);
  k_bnfin<<<1, 256, 0, stream>>>(rdfG, rdfBe, bdfG, bdfBe, ws, N);
  k_fc<<<nT, 512, 0, stream>>>(x, fcB, ws, out, N, nT);
}